// Round 10
// baseline (3782.827 us; speedup 1.0000x reference)
//
#include <hip/hip_runtime.h>

#define SEQ_T 2048
#define BATCH 64

typedef _Float16 half2v __attribute__((ext_vector_type(2)));
typedef float floatx2 __attribute__((ext_vector_type(2)));

#if defined(__has_builtin)
#  if __has_builtin(__builtin_amdgcn_fdot2)
#    define HAVE_FDOT2 1
#  endif
#endif

// f16-pair dot with f32 accumulate — builtin or exact-f32 fallback.
// NOTE: inline-asm v_dot2_f32_f16 correlated with ~0.1 absmax (R4/R5) — banned.
__device__ __forceinline__ float fdot2f(half2v a, half2v b, float c) {
#ifdef HAVE_FDOT2
  return __builtin_amdgcn_fdot2(a, b, c, false);
#else
  return c + (float)a[0] * (float)b[0] + (float)a[1] * (float)b[1];
#endif
}

__device__ __forceinline__ floatx2 fma2(floatx2 a, floatx2 b, floatx2 c) {
#if __has_builtin(__builtin_elementwise_fma)
  return __builtin_elementwise_fma(a, b, c);   // v_pk_fma_f32
#else
  floatx2 r;
  r.x = __builtin_fmaf(a.x, b.x, c.x);
  r.y = __builtin_fmaf(a.y, b.y, c.y);
  return r;
#endif
}

__device__ __forceinline__ unsigned int h2u(half2v v) { return __builtin_bit_cast(unsigned int, v); }
__device__ __forceinline__ half2v u2h(unsigned int u) { return __builtin_bit_cast(half2v, u); }

// Lane permutes on the VALU (DPP) — no LDS pipe.
template <int CTRL>
__device__ __forceinline__ float qperm(float x) {
  int xi = __builtin_bit_cast(int, x);
  int ri = __builtin_amdgcn_update_dpp(xi, xi, CTRL, 0xF, 0xF, true);
  return __builtin_bit_cast(float, ri);
}
#define QP_XOR1   0xB1   // quad_perm [1,0,3,2]
#define QP_XOR2   0x4E   // quad_perm [2,3,0,1]
#define QP_B0     0x00
#define QP_B1     0x55
#define QP_B2     0xAA
#define QP_B3     0xFF
#define QP_HMIRR  0x141  // row_half_mirror: l -> l^7 within each 8-lane group

// ---------------------------------------------------------------------------
// xproj GEMM (R2/R3-proven, unchanged): xp[tb][r*4+g] gate-interleaved f16.
// ---------------------------------------------------------------------------
template <int K, bool IN_F32>
__global__ __launch_bounds__(512) void xproj_gemm(
    const void* __restrict__ Xv,            // [M][K] f32 or f16
    const float* __restrict__ W,            // [512][K] f32
    const float* __restrict__ bih, const float* __restrict__ bhh,
    unsigned short* __restrict__ xp)        // [M][512] f16, gate-interleaved
{
  constexpr int MT = 64;
  const int g = threadIdx.x;
  const size_t m0 = (size_t)blockIdx.x * MT;

  __shared__ __align__(16) _Float16 xs[MT * K];

  if constexpr (IN_F32) {
    constexpr int PER = MT * K / 512;
    const float* Xf = (const float*)Xv + m0 * K + (size_t)g * PER;
    _Float16* dst = xs + g * PER;
#pragma unroll
    for (int i = 0; i < PER; i += 4) {
      float4 v = *reinterpret_cast<const float4*>(Xf + i);
      half2v h01; h01[0] = (_Float16)v.x; h01[1] = (_Float16)v.y;
      half2v h23; h23[0] = (_Float16)v.z; h23[1] = (_Float16)v.w;
      uint2 u; u.x = h2u(h01); u.y = h2u(h23);
      *reinterpret_cast<uint2*>(dst + i) = u;
    }
  } else {
    constexpr int PER = MT * K / 512;
    const unsigned short* Xh = (const unsigned short*)Xv + m0 * K + (size_t)g * PER;
#pragma unroll
    for (int i = 0; i < PER / 8; i++)
      reinterpret_cast<uint4*>(xs + g * PER)[i] = reinterpret_cast<const uint4*>(Xh)[i];
  }

  half2v wr[K / 2];
  {
    const float2* p = reinterpret_cast<const float2*>(W + (size_t)g * K);
#pragma unroll
    for (int k = 0; k < K / 2; k++) {
      float2 f = p[k];
      half2v v; v[0] = (_Float16)f.x; v[1] = (_Float16)f.y;
      wr[k] = v;
    }
  }
  const float bias = bih[g] + bhh[g];
  const int out_off = (g & 127) * 4 + (g >> 7);
  __syncthreads();

#pragma unroll 1
  for (int tb = 0; tb < MT; tb++) {
    const uint4* xv = reinterpret_cast<const uint4*>(xs + tb * K);
    float a0 = bias, a1 = 0.f, a2 = 0.f, a3 = 0.f;
#pragma unroll
    for (int i = 0; i < K / 8; i++) {
      const uint4 u = xv[i];
      a0 = fdot2f(wr[4 * i + 0], u2h(u.x), a0);
      a1 = fdot2f(wr[4 * i + 1], u2h(u.y), a1);
      a2 = fdot2f(wr[4 * i + 2], u2h(u.z), a2);
      a3 = fdot2f(wr[4 * i + 3], u2h(u.w), a3);
    }
    const float s = (a0 + a1) + (a2 + a3);
    xp[(m0 + tb) * 512 + out_off] = __builtin_bit_cast(unsigned short, (_Float16)s);
  }
}

// ---------------------------------------------------------------------------
// Recurrence R10: 1024 threads per WG, one WG per batch element.
// thread = (row r = tid>>3, octet lane o = tid&7). Each thread: 4 gates x
// 16 h-elems as f32 (64 VGPR, pk_fma -> 32 instr). Octet reduction all-DPP:
// in-quad reduce-scatter with per-quad gate map m(o)={0,1,2,3,3,2,1,0}
// (mirror partner o^7 holds the SAME gate), row_half_mirror adds the other
// quad, one activation per lane, 4 quad-broadcasts + selects to gather.
// h in LDS chunk-skewed x20 floats: the 8-address ds_read_b128 pattern
// covers all 32 banks exactly once (conflict-free).
// ---------------------------------------------------------------------------
struct StepCtx {
  bool t0, t1, qsel, writer;
  int hidx;
  float sc, am, ab;
};

__device__ __forceinline__ float sigmoid_fast(float x) {
  return 1.f / (1.f + __expf(-x));
}

__device__ __forceinline__ void lstm_step(
    int cur, const StepCtx& cx,
    const floatx2 (&wf)[4][8], float (&hbuf)[2][160], int o,
    unsigned short& pf, const unsigned short*& pf_ptr,
    float& c, unsigned short*& hout_ptr)
{
  // consume 2-steps-ago prefetch; immediately re-issue 2 ahead
  const float xpv = (float)__builtin_bit_cast(_Float16, pf);
  pf = *pf_ptr;
  pf_ptr += 2 * BATCH * 512;

  const float4* hv = reinterpret_cast<const float4*>(&hbuf[cur][o * 20]);
  floatx2 acc0 = {0.f, 0.f}, acc1 = {0.f, 0.f}, acc2 = {0.f, 0.f}, acc3 = {0.f, 0.f};
#pragma unroll
  for (int i = 0; i < 4; i++) {
    const float4 u = hv[i];
    floatx2 lo; lo.x = u.x; lo.y = u.y;
    floatx2 hi; hi.x = u.z; hi.y = u.w;
    acc0 = fma2(wf[0][2 * i], lo, acc0); acc0 = fma2(wf[0][2 * i + 1], hi, acc0);
    acc1 = fma2(wf[1][2 * i], lo, acc1); acc1 = fma2(wf[1][2 * i + 1], hi, acc1);
    acc2 = fma2(wf[2][2 * i], lo, acc2); acc2 = fma2(wf[2][2 * i + 1], hi, acc2);
    acc3 = fma2(wf[3][2 * i], lo, acc3); acc3 = fma2(wf[3][2 * i + 1], hi, acc3);
  }
  const float a0 = acc0.x + acc0.y;
  const float a1 = acc1.x + acc1.y;
  const float a2 = acc2.x + acc2.y;
  const float a3 = acc3.x + acc3.y;

  // in-quad reduce-scatter: lane ends with gate m(o) summed over its quad.
  // t0/t1 = bit0/bit1 of m(o). Send what the partner keeps, keep own target.
  const float s0 = cx.t0 ? a0 : a1;
  const float r0 = qperm<QP_XOR1>(s0);
  const float kA = (cx.t0 ? a1 : a0) + r0;      // gate (2*0 + t0) over pair
  const float s1 = cx.t0 ? a2 : a3;
  const float r1 = qperm<QP_XOR1>(s1);
  const float kB = (cx.t0 ? a3 : a2) + r1;      // gate (2 + t0) over pair
  const float s2 = cx.t1 ? kA : kB;
  const float r2 = qperm<QP_XOR2>(s2);
  const float sq = (cx.t1 ? kB : kA) + r2;      // gate m(o) over the quad
  // cross-quad: partner o^7 holds the same gate (by m's construction)
  const float sm = sq + qperm<QP_HMIRR>(sq);
  const float sum = sm + xpv;

  // ONE activation per lane: y = am * sigmoid(sc*sum) + ab
  const float y = cx.am * sigmoid_fast(cx.sc * sum) + cx.ab;

  // gather all 4 gates: quad0 holds gates 0,1,2,3 at pos 0..3; quad1 reversed
  const float b0v = qperm<QP_B0>(y);
  const float b1v = qperm<QP_B1>(y);
  const float b2v = qperm<QP_B2>(y);
  const float b3v = qperm<QP_B3>(y);
  const float gi = cx.qsel ? b3v : b0v;
  const float gf = cx.qsel ? b2v : b1v;
  const float gg = cx.qsel ? b1v : b2v;
  const float go = cx.qsel ? b0v : b3v;

  c = gf * c + gi * gg;
  const float th = 2.f * sigmoid_fast(2.f * c) - 1.f;
  const float h = go * th;

  if (cx.writer) {
    hbuf[cur ^ 1][cx.hidx] = h;
    *hout_ptr = __builtin_bit_cast(unsigned short, (_Float16)h);
  }
  hout_ptr += BATCH * 128;

  __syncthreads();
}

__global__ __launch_bounds__(1024)
__attribute__((amdgpu_waves_per_eu(4, 4)))
void lstm_rec3(
    const float* __restrict__ Whh,          // [512][128] f32
    const unsigned short* __restrict__ xp,  // [T*B][512] f16 gate-interleaved
    unsigned short* __restrict__ hout)      // [T*B][128] f16
{
  const int b = blockIdx.x;
  const int tid = threadIdx.x;
  const int r = tid >> 3;                   // row 0..127
  const int o = tid & 7;                    // octet lane
  const int m = (o < 4) ? o : (7 - o);      // this lane's gate

  __shared__ __align__(16) float hbuf[2][160];  // 8 chunks x 20 (skewed)

  // Whh rows for the 4 gates of row r, h-elems [o*16, o*16+16), f32 pairs
  floatx2 wf[4][8];
#pragma unroll
  for (int g = 0; g < 4; g++) {
    const float4* p = reinterpret_cast<const float4*>(
        Whh + ((size_t)(g * 128 + r)) * 128 + o * 16);
#pragma unroll
    for (int k = 0; k < 4; k++) {
      float4 f = p[k];
      floatx2 lo; lo.x = f.x; lo.y = f.y;
      floatx2 hi; hi.x = f.z; hi.y = f.w;
      wf[g][2 * k] = lo;
      wf[g][2 * k + 1] = hi;
    }
  }

  StepCtx cx;
  cx.t0 = (m & 1) != 0;
  cx.t1 = (m & 2) != 0;
  cx.qsel = (o >= 4);
  cx.writer = (o == 0);
  cx.hidx = (r >> 4) * 20 + (r & 15);
  cx.sc = (m == 2) ? 2.f : 1.f;
  cx.am = (m == 2) ? 2.f : 1.f;
  cx.ab = (m == 2) ? -1.f : 0.f;

  if (tid < 160) hbuf[0][tid] = 0.f;

  const unsigned short* xpb = xp + (size_t)b * 512 + (r * 4 + m);
  unsigned short pfa = xpb[0];
  unsigned short pfb = xpb[(size_t)1 * (BATCH * 512)];
  const unsigned short* pA = xpb + (size_t)2 * (BATCH * 512);
  const unsigned short* pB = xpb + (size_t)3 * (BATCH * 512);
  unsigned short* houtp = hout + (size_t)b * 128 + r;
  float c = 0.f;
  __syncthreads();

#pragma unroll 1
  for (int t = 0; t < SEQ_T; t += 2) {
    lstm_step(0, cx, wf, hbuf, o, pfa, pA, c, houtp);
    lstm_step(1, cx, wf, hbuf, o, pfb, pB, c, houtp);
  }
}

// ---------------------------------------------------------------------------
// Final linear: out[tb] = h1[tb]·wlin + blin  (R3-proven)
// ---------------------------------------------------------------------------
__global__ __launch_bounds__(256) void final_lin(
    const unsigned short* __restrict__ h1,  // [T*B][128] f16
    const float* __restrict__ Wlin, const float* __restrict__ blin,
    float* __restrict__ out)
{
  const size_t tb = (size_t)blockIdx.x * 256 + threadIdx.x;
  half2v wl[64];
  const float2* p = reinterpret_cast<const float2*>(Wlin);
#pragma unroll
  for (int k = 0; k < 64; k++) {
    float2 f = p[k];
    half2v v; v[0] = (_Float16)f.x; v[1] = (_Float16)f.y;
    wl[k] = v;
  }
  const uint4* hv = reinterpret_cast<const uint4*>(h1 + tb * 128);
  float a0 = 0.f, a1 = 0.f, a2 = 0.f, a3 = 0.f;
#pragma unroll
  for (int i = 0; i < 16; i++) {
    const uint4 u = hv[i];
    a0 = fdot2f(wl[4 * i + 0], u2h(u.x), a0);
    a1 = fdot2f(wl[4 * i + 1], u2h(u.y), a1);
    a2 = fdot2f(wl[4 * i + 2], u2h(u.z), a2);
    a3 = fdot2f(wl[4 * i + 3], u2h(u.w), a3);
  }
  out[tb] = (a0 + a1) + (a2 + a3) + blin[0];
}

extern "C" void kernel_launch(void* const* d_in, const int* in_sizes, int n_in,
                              void* d_out, int out_size, void* d_ws, size_t ws_size,
                              hipStream_t stream) {
  (void)in_sizes; (void)n_in; (void)out_size; (void)ws_size;

  const float* data = (const float*)d_in[0];
  const float* Wih0 = (const float*)d_in[1];
  const float* Whh0 = (const float*)d_in[2];
  const float* bih0 = (const float*)d_in[3];
  const float* bhh0 = (const float*)d_in[4];
  const float* Wih1 = (const float*)d_in[5];
  const float* Whh1 = (const float*)d_in[6];
  const float* bih1 = (const float*)d_in[7];
  const float* bhh1 = (const float*)d_in[8];
  const float* Wlin = (const float*)d_in[9];
  const float* blin = (const float*)d_in[10];

  // ws layout: xp 128 MiB | h0 32 MiB | h1 32 MiB
  unsigned char* ws = (unsigned char*)d_ws;
  unsigned short* xpb = (unsigned short*)ws;
  unsigned short* h0 = (unsigned short*)(ws + (size_t)128 * 1024 * 1024);
  unsigned short* h1 = (unsigned short*)(ws + (size_t)160 * 1024 * 1024);

  const int M = SEQ_T * BATCH;
  const int gemm_blocks = M / 64;

  xproj_gemm<64, true><<<dim3(gemm_blocks), dim3(512), 0, stream>>>(
      data, Wih0, bih0, bhh0, xpb);
  lstm_rec3<<<dim3(BATCH), dim3(1024), 0, stream>>>(Whh0, xpb, h0);
  xproj_gemm<128, false><<<dim3(gemm_blocks), dim3(512), 0, stream>>>(
      h0, Wih1, bih1, bhh1, xpb);
  lstm_rec3<<<dim3(BATCH), dim3(1024), 0, stream>>>(Whh1, xpb, h1);
  final_lin<<<dim3(M / 256), dim3(256), 0, stream>>>(h1, Wlin, blin, (float*)d_out);
}

// Round 11
// 3763.581 us; speedup vs baseline: 1.0051x; 1.0051x over previous
//
#include <hip/hip_runtime.h>

#define SEQ_T 2048
#define BATCH 64

typedef _Float16 half2v __attribute__((ext_vector_type(2)));
typedef float floatx2 __attribute__((ext_vector_type(2)));

#if defined(__has_builtin)
#  if __has_builtin(__builtin_amdgcn_fdot2)
#    define HAVE_FDOT2 1
#  endif
#endif

// f16-pair dot with f32 accumulate — builtin or exact-f32 fallback.
// NOTE: inline-asm v_dot2_f32_f16 correlated with ~0.1 absmax (R4/R5) — banned.
__device__ __forceinline__ float fdot2f(half2v a, half2v b, float c) {
#ifdef HAVE_FDOT2
  return __builtin_amdgcn_fdot2(a, b, c, false);
#else
  return c + (float)a[0] * (float)b[0] + (float)a[1] * (float)b[1];
#endif
}

__device__ __forceinline__ floatx2 fma2(floatx2 a, floatx2 b, floatx2 c) {
#if __has_builtin(__builtin_elementwise_fma)
  return __builtin_elementwise_fma(a, b, c);   // v_pk_fma_f32
#else
  floatx2 r;
  r.x = __builtin_fmaf(a.x, b.x, c.x);
  r.y = __builtin_fmaf(a.y, b.y, c.y);
  return r;
#endif
}

__device__ __forceinline__ unsigned int h2u(half2v v) { return __builtin_bit_cast(unsigned int, v); }
__device__ __forceinline__ half2v u2h(unsigned int u) { return __builtin_bit_cast(half2v, u); }

// Lane permutes on the VALU (DPP) — no LDS pipe.
template <int CTRL>
__device__ __forceinline__ float qperm(float x) {
  int xi = __builtin_bit_cast(int, x);
  int ri = __builtin_amdgcn_update_dpp(xi, xi, CTRL, 0xF, 0xF, true);
  return __builtin_bit_cast(float, ri);
}
#define QP_XOR1   0xB1   // quad_perm [1,0,3,2]
#define QP_XOR2   0x4E   // quad_perm [2,3,0,1]
#define QP_B0     0x00
#define QP_B1     0x55
#define QP_B2     0xAA
#define QP_B3     0xFF
#define QP_HMIRR  0x141  // row_half_mirror: l -> l^7 within each 8-lane group

// ---------------------------------------------------------------------------
// xproj GEMM (R2/R3-proven, unchanged): xp[tb][r*4+g] gate-interleaved f16.
// ---------------------------------------------------------------------------
template <int K, bool IN_F32>
__global__ __launch_bounds__(512) void xproj_gemm(
    const void* __restrict__ Xv,            // [M][K] f32 or f16
    const float* __restrict__ W,            // [512][K] f32
    const float* __restrict__ bih, const float* __restrict__ bhh,
    unsigned short* __restrict__ xp)        // [M][512] f16, gate-interleaved
{
  constexpr int MT = 64;
  const int g = threadIdx.x;
  const size_t m0 = (size_t)blockIdx.x * MT;

  __shared__ __align__(16) _Float16 xs[MT * K];

  if constexpr (IN_F32) {
    constexpr int PER = MT * K / 512;
    const float* Xf = (const float*)Xv + m0 * K + (size_t)g * PER;
    _Float16* dst = xs + g * PER;
#pragma unroll
    for (int i = 0; i < PER; i += 4) {
      float4 v = *reinterpret_cast<const float4*>(Xf + i);
      half2v h01; h01[0] = (_Float16)v.x; h01[1] = (_Float16)v.y;
      half2v h23; h23[0] = (_Float16)v.z; h23[1] = (_Float16)v.w;
      uint2 u; u.x = h2u(h01); u.y = h2u(h23);
      *reinterpret_cast<uint2*>(dst + i) = u;
    }
  } else {
    constexpr int PER = MT * K / 512;
    const unsigned short* Xh = (const unsigned short*)Xv + m0 * K + (size_t)g * PER;
#pragma unroll
    for (int i = 0; i < PER / 8; i++)
      reinterpret_cast<uint4*>(xs + g * PER)[i] = reinterpret_cast<const uint4*>(Xh)[i];
  }

  half2v wr[K / 2];
  {
    const float2* p = reinterpret_cast<const float2*>(W + (size_t)g * K);
#pragma unroll
    for (int k = 0; k < K / 2; k++) {
      float2 f = p[k];
      half2v v; v[0] = (_Float16)f.x; v[1] = (_Float16)f.y;
      wr[k] = v;
    }
  }
  const float bias = bih[g] + bhh[g];
  const int out_off = (g & 127) * 4 + (g >> 7);
  __syncthreads();

#pragma unroll 1
  for (int tb = 0; tb < MT; tb++) {
    const uint4* xv = reinterpret_cast<const uint4*>(xs + tb * K);
    float a0 = bias, a1 = 0.f, a2 = 0.f, a3 = 0.f;
#pragma unroll
    for (int i = 0; i < K / 8; i++) {
      const uint4 u = xv[i];
      a0 = fdot2f(wr[4 * i + 0], u2h(u.x), a0);
      a1 = fdot2f(wr[4 * i + 1], u2h(u.y), a1);
      a2 = fdot2f(wr[4 * i + 2], u2h(u.z), a2);
      a3 = fdot2f(wr[4 * i + 3], u2h(u.w), a3);
    }
    const float s = (a0 + a1) + (a2 + a3);
    xp[(m0 + tb) * 512 + out_off] = __builtin_bit_cast(unsigned short, (_Float16)s);
  }
}

// ---------------------------------------------------------------------------
// Recurrence R11 = R10 + asm-pinned weights.
// 1024 threads/WG, one WG per batch element; thread = (row r = tid>>3,
// octet lane o = tid&7); 4 gates x 16 h-elems as f32 (64 VGPR, pk_fma).
// R10's VGPR_Count=52 showed LLVM rematerializes pure global loads into the
// loop (R6/R8 same; R9's load+cvt values stayed resident). The volatile-asm
// "+v" pin makes each weight the output of a non-rematerializable asm ->
// forced residency.
// ---------------------------------------------------------------------------
struct StepCtx {
  bool t0, t1, qsel, writer;
  int hidx;
  float sc, am, ab;
};

__device__ __forceinline__ float sigmoid_fast(float x) {
  return 1.f / (1.f + __expf(-x));
}

__device__ __forceinline__ void lstm_step(
    int cur, const StepCtx& cx,
    const floatx2 (&wf)[4][8], float (&hbuf)[2][160], int o,
    unsigned short& pf, const unsigned short*& pf_ptr,
    float& c, unsigned short*& hout_ptr)
{
  // consume 2-steps-ago prefetch; immediately re-issue 2 ahead
  const float xpv = (float)__builtin_bit_cast(_Float16, pf);
  pf = *pf_ptr;
  pf_ptr += 2 * BATCH * 512;

  const float4* hv = reinterpret_cast<const float4*>(&hbuf[cur][o * 20]);
  floatx2 acc0 = {0.f, 0.f}, acc1 = {0.f, 0.f}, acc2 = {0.f, 0.f}, acc3 = {0.f, 0.f};
#pragma unroll
  for (int i = 0; i < 4; i++) {
    const float4 u = hv[i];
    floatx2 lo; lo.x = u.x; lo.y = u.y;
    floatx2 hi; hi.x = u.z; hi.y = u.w;
    acc0 = fma2(wf[0][2 * i], lo, acc0); acc0 = fma2(wf[0][2 * i + 1], hi, acc0);
    acc1 = fma2(wf[1][2 * i], lo, acc1); acc1 = fma2(wf[1][2 * i + 1], hi, acc1);
    acc2 = fma2(wf[2][2 * i], lo, acc2); acc2 = fma2(wf[2][2 * i + 1], hi, acc2);
    acc3 = fma2(wf[3][2 * i], lo, acc3); acc3 = fma2(wf[3][2 * i + 1], hi, acc3);
  }
  const float a0 = acc0.x + acc0.y;
  const float a1 = acc1.x + acc1.y;
  const float a2 = acc2.x + acc2.y;
  const float a3 = acc3.x + acc3.y;

  // in-quad reduce-scatter: lane ends with gate m(o) summed over its quad.
  const float s0 = cx.t0 ? a0 : a1;
  const float r0 = qperm<QP_XOR1>(s0);
  const float kA = (cx.t0 ? a1 : a0) + r0;
  const float s1 = cx.t0 ? a2 : a3;
  const float r1 = qperm<QP_XOR1>(s1);
  const float kB = (cx.t0 ? a3 : a2) + r1;
  const float s2 = cx.t1 ? kA : kB;
  const float r2 = qperm<QP_XOR2>(s2);
  const float sq = (cx.t1 ? kB : kA) + r2;      // gate m(o) over the quad
  // cross-quad: partner o^7 holds the same gate (by m's construction)
  const float sm = sq + qperm<QP_HMIRR>(sq);
  const float sum = sm + xpv;

  // ONE activation per lane: y = am * sigmoid(sc*sum) + ab
  const float y = cx.am * sigmoid_fast(cx.sc * sum) + cx.ab;

  // gather all 4 gates: quad0 holds gates 0,1,2,3 at pos 0..3; quad1 reversed
  const float b0v = qperm<QP_B0>(y);
  const float b1v = qperm<QP_B1>(y);
  const float b2v = qperm<QP_B2>(y);
  const float b3v = qperm<QP_B3>(y);
  const float gi = cx.qsel ? b3v : b0v;
  const float gf = cx.qsel ? b2v : b1v;
  const float gg = cx.qsel ? b1v : b2v;
  const float go = cx.qsel ? b0v : b3v;

  c = gf * c + gi * gg;
  const float th = 2.f * sigmoid_fast(2.f * c) - 1.f;
  const float h = go * th;

  if (cx.writer) {
    hbuf[cur ^ 1][cx.hidx] = h;
    *hout_ptr = __builtin_bit_cast(unsigned short, (_Float16)h);
  }
  hout_ptr += BATCH * 128;

  __syncthreads();
}

__global__ __launch_bounds__(1024)
__attribute__((amdgpu_waves_per_eu(4, 4)))
void lstm_rec3(
    const float* __restrict__ Whh,          // [512][128] f32
    const unsigned short* __restrict__ xp,  // [T*B][512] f16 gate-interleaved
    unsigned short* __restrict__ hout)      // [T*B][128] f16
{
  const int b = blockIdx.x;
  const int tid = threadIdx.x;
  const int r = tid >> 3;                   // row 0..127
  const int o = tid & 7;                    // octet lane
  const int m = (o < 4) ? o : (7 - o);      // this lane's gate

  __shared__ __align__(16) float hbuf[2][160];  // 8 chunks x 20 (skewed)

  // Whh rows for the 4 gates of row r, h-elems [o*16, o*16+16), f32 pairs
  floatx2 wf[4][8];
#pragma unroll
  for (int g = 0; g < 4; g++) {
    const float4* p = reinterpret_cast<const float4*>(
        Whh + ((size_t)(g * 128 + r)) * 128 + o * 16);
#pragma unroll
    for (int k = 0; k < 4; k++) {
      float4 f = p[k];
      floatx2 lo; lo.x = f.x; lo.y = f.y;
      floatx2 hi; hi.x = f.z; hi.y = f.w;
      wf[g][2 * k] = lo;
      wf[g][2 * k + 1] = hi;
    }
  }
  // Pin weights in VGPRs: outputs of volatile asm cannot be rematerialized
  // or sunk into the loop (the R6/R8/R10 failure mode).
#pragma unroll
  for (int g = 0; g < 4; g++)
#pragma unroll
    for (int k = 0; k < 8; k++)
      asm volatile("" : "+v"(wf[g][k]));

  StepCtx cx;
  cx.t0 = (m & 1) != 0;
  cx.t1 = (m & 2) != 0;
  cx.qsel = (o >= 4);
  cx.writer = (o == 0);
  cx.hidx = (r >> 4) * 20 + (r & 15);
  cx.sc = (m == 2) ? 2.f : 1.f;
  cx.am = (m == 2) ? 2.f : 1.f;
  cx.ab = (m == 2) ? -1.f : 0.f;

  if (tid < 160) hbuf[0][tid] = 0.f;

  const unsigned short* xpb = xp + (size_t)b * 512 + (r * 4 + m);
  unsigned short pfa = xpb[0];
  unsigned short pfb = xpb[(size_t)1 * (BATCH * 512)];
  const unsigned short* pA = xpb + (size_t)2 * (BATCH * 512);
  const unsigned short* pB = xpb + (size_t)3 * (BATCH * 512);
  unsigned short* houtp = hout + (size_t)b * 128 + r;
  float c = 0.f;
  __syncthreads();

#pragma unroll 1
  for (int t = 0; t < SEQ_T; t += 2) {
    lstm_step(0, cx, wf, hbuf, o, pfa, pA, c, houtp);
    lstm_step(1, cx, wf, hbuf, o, pfb, pB, c, houtp);
  }
}

// ---------------------------------------------------------------------------
// Final linear: out[tb] = h1[tb]·wlin + blin  (R3-proven)
// ---------------------------------------------------------------------------
__global__ __launch_bounds__(256) void final_lin(
    const unsigned short* __restrict__ h1,  // [T*B][128] f16
    const float* __restrict__ Wlin, const float* __restrict__ blin,
    float* __restrict__ out)
{
  const size_t tb = (size_t)blockIdx.x * 256 + threadIdx.x;
  half2v wl[64];
  const float2* p = reinterpret_cast<const float2*>(Wlin);
#pragma unroll
  for (int k = 0; k < 64; k++) {
    float2 f = p[k];
    half2v v; v[0] = (_Float16)f.x; v[1] = (_Float16)f.y;
    wl[k] = v;
  }
  const uint4* hv = reinterpret_cast<const uint4*>(h1 + tb * 128);
  float a0 = 0.f, a1 = 0.f, a2 = 0.f, a3 = 0.f;
#pragma unroll
  for (int i = 0; i < 16; i++) {
    const uint4 u = hv[i];
    a0 = fdot2f(wl[4 * i + 0], u2h(u.x), a0);
    a1 = fdot2f(wl[4 * i + 1], u2h(u.y), a1);
    a2 = fdot2f(wl[4 * i + 2], u2h(u.z), a2);
    a3 = fdot2f(wl[4 * i + 3], u2h(u.w), a3);
  }
  out[tb] = (a0 + a1) + (a2 + a3) + blin[0];
}

extern "C" void kernel_launch(void* const* d_in, const int* in_sizes, int n_in,
                              void* d_out, int out_size, void* d_ws, size_t ws_size,
                              hipStream_t stream) {
  (void)in_sizes; (void)n_in; (void)out_size; (void)ws_size;

  const float* data = (const float*)d_in[0];
  const float* Wih0 = (const float*)d_in[1];
  const float* Whh0 = (const float*)d_in[2];
  const float* bih0 = (const float*)d_in[3];
  const float* bhh0 = (const float*)d_in[4];
  const float* Wih1 = (const float*)d_in[5];
  const float* Whh1 = (const float*)d_in[6];
  const float* bih1 = (const float*)d_in[7];
  const float* bhh1 = (const float*)d_in[8];
  const float* Wlin = (const float*)d_in[9];
  const float* blin = (const float*)d_in[10];

  // ws layout: xp 128 MiB | h0 32 MiB | h1 32 MiB
  unsigned char* ws = (unsigned char*)d_ws;
  unsigned short* xpb = (unsigned short*)ws;
  unsigned short* h0 = (unsigned short*)(ws + (size_t)128 * 1024 * 1024);
  unsigned short* h1 = (unsigned short*)(ws + (size_t)160 * 1024 * 1024);

  const int M = SEQ_T * BATCH;
  const int gemm_blocks = M / 64;

  xproj_gemm<64, true><<<dim3(gemm_blocks), dim3(512), 0, stream>>>(
      data, Wih0, bih0, bhh0, xpb);
  lstm_rec3<<<dim3(BATCH), dim3(1024), 0, stream>>>(Whh0, xpb, h0);
  xproj_gemm<128, false><<<dim3(gemm_blocks), dim3(512), 0, stream>>>(
      h0, Wih1, bih1, bhh1, xpb);
  lstm_rec3<<<dim3(BATCH), dim3(1024), 0, stream>>>(Whh1, xpb, h1);
  final_lin<<<dim3(M / 256), dim3(256), 0, stream>>>(h1, Wlin, blin, (float*)d_out);
}

// Round 12
// 2888.319 us; speedup vs baseline: 1.3097x; 1.3030x over previous
//
#include <hip/hip_runtime.h>

#define SEQ_T 2048
#define BATCH 64

typedef _Float16 half2v __attribute__((ext_vector_type(2)));
typedef float floatx2 __attribute__((ext_vector_type(2)));

#if defined(__has_builtin)
#  if __has_builtin(__builtin_amdgcn_fdot2)
#    define HAVE_FDOT2 1
#  endif
#endif

// f16-pair dot with f32 accumulate — builtin or exact-f32 fallback.
// NOTE: inline-asm v_dot2_f32_f16 correlated with ~0.1 absmax (R4/R5) — banned.
__device__ __forceinline__ float fdot2f(half2v a, half2v b, float c) {
#ifdef HAVE_FDOT2
  return __builtin_amdgcn_fdot2(a, b, c, false);
#else
  return c + (float)a[0] * (float)b[0] + (float)a[1] * (float)b[1];
#endif
}

__device__ __forceinline__ floatx2 fma2(floatx2 a, floatx2 b, floatx2 c) {
#if __has_builtin(__builtin_elementwise_fma)
  return __builtin_elementwise_fma(a, b, c);   // v_pk_fma_f32
#else
  floatx2 r;
  r.x = __builtin_fmaf(a.x, b.x, c.x);
  r.y = __builtin_fmaf(a.y, b.y, c.y);
  return r;
#endif
}

__device__ __forceinline__ unsigned int h2u(half2v v) { return __builtin_bit_cast(unsigned int, v); }
__device__ __forceinline__ half2v u2h(unsigned int u) { return __builtin_bit_cast(half2v, u); }

// Lane permutes on the VALU (DPP) — no LDS pipe.
template <int CTRL>
__device__ __forceinline__ float qperm(float x) {
  int xi = __builtin_bit_cast(int, x);
  int ri = __builtin_amdgcn_update_dpp(xi, xi, CTRL, 0xF, 0xF, true);
  return __builtin_bit_cast(float, ri);
}
#define QP_XOR1   0xB1   // quad_perm [1,0,3,2]
#define QP_XOR2   0x4E   // quad_perm [2,3,0,1]
#define QP_B0     0x00
#define QP_B1     0x55
#define QP_B2     0xAA
#define QP_B3     0xFF

// In-loop residency pin: each iteration the weights become outputs of this
// asm, so they can never be rematerialized as loads, and spilling would cost
// 16 scratch round-trips per statement per step — the allocator keeps them
// in VGPRs. (R11 proved the *outside-loop* pin is insufficient.)
#define PIN16(W, G)                                                          \
  asm volatile("" : "+v"((W)[G][0]), "+v"((W)[G][1]), "+v"((W)[G][2]),       \
                    "+v"((W)[G][3]), "+v"((W)[G][4]), "+v"((W)[G][5]),       \
                    "+v"((W)[G][6]), "+v"((W)[G][7]), "+v"((W)[G][8]),       \
                    "+v"((W)[G][9]), "+v"((W)[G][10]), "+v"((W)[G][11]),     \
                    "+v"((W)[G][12]), "+v"((W)[G][13]), "+v"((W)[G][14]),    \
                    "+v"((W)[G][15]))

// ---------------------------------------------------------------------------
// xproj GEMM (R2/R3-proven, unchanged): xp[tb][r*4+g] gate-interleaved f16.
// ---------------------------------------------------------------------------
template <int K, bool IN_F32>
__global__ __launch_bounds__(512) void xproj_gemm(
    const void* __restrict__ Xv,            // [M][K] f32 or f16
    const float* __restrict__ W,            // [512][K] f32
    const float* __restrict__ bih, const float* __restrict__ bhh,
    unsigned short* __restrict__ xp)        // [M][512] f16, gate-interleaved
{
  constexpr int MT = 64;
  const int g = threadIdx.x;
  const size_t m0 = (size_t)blockIdx.x * MT;

  __shared__ __align__(16) _Float16 xs[MT * K];

  if constexpr (IN_F32) {
    constexpr int PER = MT * K / 512;
    const float* Xf = (const float*)Xv + m0 * K + (size_t)g * PER;
    _Float16* dst = xs + g * PER;
#pragma unroll
    for (int i = 0; i < PER; i += 4) {
      float4 v = *reinterpret_cast<const float4*>(Xf + i);
      half2v h01; h01[0] = (_Float16)v.x; h01[1] = (_Float16)v.y;
      half2v h23; h23[0] = (_Float16)v.z; h23[1] = (_Float16)v.w;
      uint2 u; u.x = h2u(h01); u.y = h2u(h23);
      *reinterpret_cast<uint2*>(dst + i) = u;
    }
  } else {
    constexpr int PER = MT * K / 512;
    const unsigned short* Xh = (const unsigned short*)Xv + m0 * K + (size_t)g * PER;
#pragma unroll
    for (int i = 0; i < PER / 8; i++)
      reinterpret_cast<uint4*>(xs + g * PER)[i] = reinterpret_cast<const uint4*>(Xh)[i];
  }

  half2v wr[K / 2];
  {
    const float2* p = reinterpret_cast<const float2*>(W + (size_t)g * K);
#pragma unroll
    for (int k = 0; k < K / 2; k++) {
      float2 f = p[k];
      half2v v; v[0] = (_Float16)f.x; v[1] = (_Float16)f.y;
      wr[k] = v;
    }
  }
  const float bias = bih[g] + bhh[g];
  const int out_off = (g & 127) * 4 + (g >> 7);
  __syncthreads();

#pragma unroll 1
  for (int tb = 0; tb < MT; tb++) {
    const uint4* xv = reinterpret_cast<const uint4*>(xs + tb * K);
    float a0 = bias, a1 = 0.f, a2 = 0.f, a3 = 0.f;
#pragma unroll
    for (int i = 0; i < K / 8; i++) {
      const uint4 u = xv[i];
      a0 = fdot2f(wr[4 * i + 0], u2h(u.x), a0);
      a1 = fdot2f(wr[4 * i + 1], u2h(u.y), a1);
      a2 = fdot2f(wr[4 * i + 2], u2h(u.z), a2);
      a3 = fdot2f(wr[4 * i + 3], u2h(u.w), a3);
    }
    const float s = (a0 + a1) + (a2 + a3);
    xp[(m0 + tb) * 512 + out_off] = __builtin_bit_cast(unsigned short, (_Float16)s);
  }
}

// ---------------------------------------------------------------------------
// Recurrence R12 = R9 structure (512 thr, DPP quad reduce, skewed hbuf) with
// f32 weights (pk_fma: 64 instr for 128 MACs vs R9's ~256 cvt+fma) and the
// IN-LOOP residency pin (see PIN16).
// thread = (row r = wave*16 + (l>>2), K-split ks = l&3).
// ---------------------------------------------------------------------------
struct StepCtx {
  int ks, r, hidx;
  float sc, am, ab;
  bool writer;
};

__device__ __forceinline__ float sigmoid_fast(float x) {
  return 1.f / (1.f + __expf(-x));
}

__device__ __forceinline__ void lstm_step(
    int cur, const StepCtx& cx,
    floatx2 (&wh)[4][16], float (&hbuf)[2][144],
    unsigned short& pf, const unsigned short*& pf_ptr,
    float& c, unsigned short*& hout_ptr)
{
  // re-pin weights this iteration (forces VGPR residency; see PIN16 comment)
  PIN16(wh, 0); PIN16(wh, 1); PIN16(wh, 2); PIN16(wh, 3);

  // consume 2-steps-ago prefetch; immediately re-issue 2 ahead
  const float xpv = (float)__builtin_bit_cast(_Float16, pf);
  pf = *pf_ptr;
  pf_ptr += 2 * BATCH * 512;

  floatx2 acc0 = {0.f, 0.f}, acc1 = {0.f, 0.f}, acc2 = {0.f, 0.f}, acc3 = {0.f, 0.f};
  const float4* hv = reinterpret_cast<const float4*>(&hbuf[cur][cx.ks * 36]);
#pragma unroll
  for (int i = 0; i < 8; i++) {
    const float4 u = hv[i];
    floatx2 lo; lo.x = u.x; lo.y = u.y;
    floatx2 hi; hi.x = u.z; hi.y = u.w;
    acc0 = fma2(wh[0][2 * i], lo, acc0); acc0 = fma2(wh[0][2 * i + 1], hi, acc0);
    acc1 = fma2(wh[1][2 * i], lo, acc1); acc1 = fma2(wh[1][2 * i + 1], hi, acc1);
    acc2 = fma2(wh[2][2 * i], lo, acc2); acc2 = fma2(wh[2][2 * i + 1], hi, acc2);
    acc3 = fma2(wh[3][2 * i], lo, acc3); acc3 = fma2(wh[3][2 * i + 1], hi, acc3);
  }
  const float a0 = acc0.x + acc0.y;
  const float a1 = acc1.x + acc1.y;
  const float a2 = acc2.x + acc2.y;
  const float a3 = acc3.x + acc3.y;

  // quad reduce-scatter via DPP: lane ks ends with the full sum of gate ks
  const bool q0 = (cx.ks & 1) != 0, q1 = (cx.ks & 2) != 0;
  float s0 = q0 ? a0 : a1;
  float s1 = q0 ? a2 : a3;
  float r0 = qperm<QP_XOR1>(s0);
  float r1 = qperm<QP_XOR1>(s1);
  float kA = (q0 ? a1 : a0) + r0;
  float kB = (q0 ? a3 : a2) + r1;
  float s2 = q1 ? kA : kB;
  float r2 = qperm<QP_XOR2>(s2);
  float sum = (q1 ? kB : kA) + r2 + xpv;

  // ONE activation per lane: y = am * sigmoid(sc*sum) + ab
  float y = cx.am * sigmoid_fast(cx.sc * sum) + cx.ab;

  // all-gather activated gates across the quad via DPP broadcasts
  float gi = qperm<QP_B0>(y);
  float gf = qperm<QP_B1>(y);
  float gg = qperm<QP_B2>(y);
  float go = qperm<QP_B3>(y);

  c = gf * c + gi * gg;
  float th = 2.f * sigmoid_fast(2.f * c) - 1.f;
  float h = go * th;

  if (cx.writer) {
    hbuf[cur ^ 1][cx.hidx] = h;
    *hout_ptr = __builtin_bit_cast(unsigned short, (_Float16)h);
  }
  hout_ptr += BATCH * 128;

  __syncthreads();
}

__global__ __launch_bounds__(512)
__attribute__((amdgpu_waves_per_eu(2, 2)))
void lstm_rec2(
    const float* __restrict__ Whh,          // [512][128] f32
    const unsigned short* __restrict__ xp,  // [T*B][512] f16 gate-interleaved
    unsigned short* __restrict__ hout)      // [T*B][128] f16
{
  const int b = blockIdx.x;
  const int tid = threadIdx.x;
  const int l = tid & 63;
  const int w = tid >> 6;
  const int rr = l >> 2;
  const int ks = l & 3;
  const int r = w * 16 + rr;

  __shared__ __align__(16) float hbuf[2][144];   // 4 chunks x 36 (skewed)

  // Whh rows for this thread's 4 gates, chunk ks*32..+32, as f32 pairs
  floatx2 wh[4][16];
#pragma unroll
  for (int g = 0; g < 4; g++) {
    const float4* p = reinterpret_cast<const float4*>(
        Whh + ((size_t)(g * 128 + r)) * 128 + ks * 32);
#pragma unroll
    for (int k = 0; k < 8; k++) {
      float4 f = p[k];
      floatx2 lo; lo.x = f.x; lo.y = f.y;
      floatx2 hi; hi.x = f.z; hi.y = f.w;
      wh[g][2 * k] = lo;
      wh[g][2 * k + 1] = hi;
    }
  }

  StepCtx cx;
  cx.ks = ks; cx.r = r;
  cx.hidx = (r >> 5) * 36 + (r & 31);
  cx.sc = (ks == 2) ? 2.f : 1.f;
  cx.am = (ks == 2) ? 2.f : 1.f;
  cx.ab = (ks == 2) ? -1.f : 0.f;
  cx.writer = (ks == 0);

  if (tid < 144) { hbuf[0][tid] = 0.f; }

  const unsigned short* xpb = xp + (size_t)b * 512 + tid;  // tid == r*4+ks
  unsigned short pfa = xpb[0];
  unsigned short pfb = xpb[(size_t)1 * (BATCH * 512)];
  const unsigned short* pA = xpb + (size_t)2 * (BATCH * 512);
  const unsigned short* pB = xpb + (size_t)3 * (BATCH * 512);
  unsigned short* houtp = hout + (size_t)b * 128 + r;
  float c = 0.f;
  __syncthreads();

#pragma unroll 1
  for (int t = 0; t < SEQ_T; t += 2) {
    lstm_step(0, cx, wh, hbuf, pfa, pA, c, houtp);
    lstm_step(1, cx, wh, hbuf, pfb, pB, c, houtp);
  }
}

// ---------------------------------------------------------------------------
// Final linear: out[tb] = h1[tb]·wlin + blin  (R3-proven)
// ---------------------------------------------------------------------------
__global__ __launch_bounds__(256) void final_lin(
    const unsigned short* __restrict__ h1,  // [T*B][128] f16
    const float* __restrict__ Wlin, const float* __restrict__ blin,
    float* __restrict__ out)
{
  const size_t tb = (size_t)blockIdx.x * 256 + threadIdx.x;
  half2v wl[64];
  const float2* p = reinterpret_cast<const float2*>(Wlin);
#pragma unroll
  for (int k = 0; k < 64; k++) {
    float2 f = p[k];
    half2v v; v[0] = (_Float16)f.x; v[1] = (_Float16)f.y;
    wl[k] = v;
  }
  const uint4* hv = reinterpret_cast<const uint4*>(h1 + tb * 128);
  float a0 = 0.f, a1 = 0.f, a2 = 0.f, a3 = 0.f;
#pragma unroll
  for (int i = 0; i < 16; i++) {
    const uint4 u = hv[i];
    a0 = fdot2f(wl[4 * i + 0], u2h(u.x), a0);
    a1 = fdot2f(wl[4 * i + 1], u2h(u.y), a1);
    a2 = fdot2f(wl[4 * i + 2], u2h(u.z), a2);
    a3 = fdot2f(wl[4 * i + 3], u2h(u.w), a3);
  }
  out[tb] = (a0 + a1) + (a2 + a3) + blin[0];
}

extern "C" void kernel_launch(void* const* d_in, const int* in_sizes, int n_in,
                              void* d_out, int out_size, void* d_ws, size_t ws_size,
                              hipStream_t stream) {
  (void)in_sizes; (void)n_in; (void)out_size; (void)ws_size;

  const float* data = (const float*)d_in[0];
  const float* Wih0 = (const float*)d_in[1];
  const float* Whh0 = (const float*)d_in[2];
  const float* bih0 = (const float*)d_in[3];
  const float* bhh0 = (const float*)d_in[4];
  const float* Wih1 = (const float*)d_in[5];
  const float* Whh1 = (const float*)d_in[6];
  const float* bih1 = (const float*)d_in[7];
  const float* bhh1 = (const float*)d_in[8];
  const float* Wlin = (const float*)d_in[9];
  const float* blin = (const float*)d_in[10];

  // ws layout: xp 128 MiB | h0 32 MiB | h1 32 MiB
  unsigned char* ws = (unsigned char*)d_ws;
  unsigned short* xpb = (unsigned short*)ws;
  unsigned short* h0 = (unsigned short*)(ws + (size_t)128 * 1024 * 1024);
  unsigned short* h1 = (unsigned short*)(ws + (size_t)160 * 1024 * 1024);

  const int M = SEQ_T * BATCH;
  const int gemm_blocks = M / 64;

  xproj_gemm<64, true><<<dim3(gemm_blocks), dim3(512), 0, stream>>>(
      data, Wih0, bih0, bhh0, xpb);
  lstm_rec2<<<dim3(BATCH), dim3(512), 0, stream>>>(Whh0, xpb, h0);
  xproj_gemm<128, false><<<dim3(gemm_blocks), dim3(512), 0, stream>>>(
      h0, Wih1, bih1, bhh1, xpb);
  lstm_rec2<<<dim3(BATCH), dim3(512), 0, stream>>>(Whh1, xpb, h1);
  final_lin<<<dim3(M / 256), dim3(256), 0, stream>>>(h1, Wlin, blin, (float*)d_out);
}